// Round 7
// baseline (132.905 us; speedup 1.0000x reference)
//
#include <hip/hip_runtime.h>

// FirUpsample R6 = R5 + coalesced float4 w-staging (the R5 stall was an
// L1-serialized scalar w-gather: 18 scalar loads/thread/chunk, ~38 cache
// lines per wave-instr -> ~73us of L1 line-transactions. float4 staging is
// byte-identical in As layout, 10x fewer line-txns).
//   Stage 1 (MFMA): h = dilated conv3x3(x, w) as 4 parity-plane GEMMs
//     (K-depth 4/2/2/1 x 256 ic => 10.3 G MAC vs 38.7 G composite form).
//   Stage 2 (VALU): separable 4-tap FIR on h (bf16 in LDS), fp32 out.

typedef short bf16x8 __attribute__((ext_vector_type(8)));
typedef short short4v __attribute__((ext_vector_type(4)));
typedef float f32x16 __attribute__((ext_vector_type(16)));
typedef float f32x4v __attribute__((ext_vector_type(4)));

static __device__ __forceinline__ short f2bf(float f) {
  union { float f; unsigned u; } v; v.f = f;
  unsigned r = (v.u + 0x7FFFu + ((v.u >> 16) & 1u)) >> 16;
  return (short)r;
}
static __device__ __forceinline__ float bf2f(short s) {
  union { unsigned u; float f; } v; v.u = ((unsigned)(unsigned short)s) << 16;
  return v.f;
}

__global__ __launch_bounds__(512)
void fir_up_v6(const float* __restrict__ x, const float* __restrict__ w,
               float* __restrict__ out) {
  // XCD swizzle: xcd = bid&7; octile-major so each XCD pair shares a w-slice.
  const int bid = blockIdx.x;
  const int wg = (bid & 7) * 64 + (bid >> 3);
  const int octile = wg >> 7;        // 0..3 (64 oc each)
  const int n = (wg >> 5) & 3;
  const int sp = wg & 31;
  const int atile = sp >> 2;         // 0..7 coarse-row tiles (8 rows each)
  const int btile = sp & 3;          // 0..3 coarse-col tiles (16 cols each)
  const int A0 = atile * 8, B0 = btile * 16;

  const int tid = threadIdx.x;
  const int wid = tid >> 6;
  const int lane = tid & 63;
  const int l31 = lane & 31, q = lane >> 5;

  __shared__ short As[9 * 64 * 16];       // [kq][oc64][ic16]  18.4 KB
  __shared__ short xs[180 * 16];          // [cell=r*18+c][ic16] 5.76 KB
  __shared__ short hl[4 * 32 * 10 * 20];  // [plane][ocl][r][c(pad 20)] 51.2 KB

  // plane geometry: p = py*2+px ; rows: even 9 odd 10 ; cols: even 17 odd 18
  const int COLSt[4]  = {17, 18, 17, 18};
  const int CELLSt[4] = {153, 162, 170, 180};
  const int NKt[4]    = {4, 2, 2, 1};
  const int KQt[4][4] = {{0,2,6,8},{1,7,7,7},{3,5,5,5},{4,4,4,4}};
  const int DYt[4][4] = {{0,0,1,1},{0,1,1,1},{0,0,0,0},{0,0,0,0}};
  const int DXt[4][4] = {{0,1,0,1},{0,0,0,0},{0,1,1,1},{0,0,0,0}};

  // per-wave frag assignment (8 waves x 3 slots), K-balanced (7,7,7,7,7,7,6,6)
  const unsigned long long PLbits =
      (0x34ULL) | (0x34ULL << 6) | (0x34ULL << 12) | (0x38ULL << 18) |
      (0x38ULL << 24) | (0x38ULL << 30) | (0x15ULL << 36) | (0x2AULL << 42);
  const unsigned FG0 = 0u | 1u<<3 | 2u<<6 | 3u<<9 | 4u<<12 | 5u<<15 | 3u<<18 | 3u<<21;
  const unsigned FG1 = 0u | 1u<<3 | 2u<<6 | 0u<<9 | 1u<<12 | 2u<<15 | 4u<<18 | 4u<<21;
  const unsigned FG2 = 0u | 1u<<3 | 2u<<6 | 3u<<9 | 4u<<12 | 5u<<15 | 5u<<18 | 5u<<21;

  int nkS[3], validS[3], hbaseS[3];
  int kqS[3][4], cellxS[3][4];
#pragma unroll
  for (int slot = 0; slot < 3; ++slot) {
    const int p = (int)((PLbits >> ((wid * 3 + slot) * 2)) & 3ULL);
    const unsigned fgw = slot == 0 ? FG0 : (slot == 1 ? FG1 : FG2);
    const int fg = (int)((fgw >> (3 * wid)) & 7u);
    const int cellraw = fg * 32 + l31;
    const int valid = cellraw < CELLSt[p];
    const int cell = valid ? cellraw : 0;
    const int cols = COLSt[p];
    const int r = cell / cols;
    const int c = cell - r * cols;
    nkS[slot] = NKt[p];
    validS[slot] = valid;
    hbaseS[slot] = p * 6400 + r * 20 + c;
#pragma unroll
    for (int s = 0; s < 4; ++s) {
      kqS[slot][s] = KQt[p][s];
      cellxS[slot][s] = (r + DYt[p][s]) * 18 + (c + DXt[p][s]);
    }
  }

  f32x16 acc[3][2];
#pragma unroll
  for (int slot = 0; slot < 3; ++slot)
#pragma unroll
    for (int mf = 0; mf < 2; ++mf)
#pragma unroll
      for (int e = 0; e < 16; ++e) acc[slot][mf][e] = 0.f;

  // w base for this octile; per oc the chunk's 144 floats (16ic x 9kq) are
  // contiguous at w + oc*2304 + cc*144, 16B-aligned.
  const float* wbase = w + (size_t)(octile * 64) * 2304;

  // ---------------- K-loop: 16 chunks of 16 ic ----------------
  for (int cc = 0; cc < 16; ++cc) {
    __syncthreads();
    // stage x tile: rows [A0-1, A0+8], cols [B0-1, B0+16] -> 10x18 cells x 16 ic
    if (tid < 360) {
      const int cell = tid >> 1, half = tid & 1;
      const int hh = cell / 18, ww = cell - hh * 18;
      const int gh = A0 - 1 + hh, gw = B0 - 1 + ww;
      const bool ok = (gh >= 0) & (gh < 64) & (gw >= 0) & (gw < 64);
      const float* xp = x + (((size_t)(n * 256 + cc * 16 + half * 8)) * 64 + gh) * 64 + gw;
      bf16x8 vv;
#pragma unroll
      for (int e = 0; e < 8; ++e) {
        const float f = ok ? xp[(size_t)e * 4096] : 0.f;
        vv[e] = f2bf(f);
      }
      *(bf16x8*)(xs + cell * 16 + half * 8) = vv;
    }
    // stage A (= w bf16): 2304 float4s, lane-consecutive -> fully coalesced.
    // float4 f: oc = f/36, f36 = f%36; element e: flat = f36*4+e in [0,144),
    // ic = flat/9, kq = flat%9  ==  w[oc][cc*16+ic][kq]  (byte-identical to R5 As)
    for (int f = tid; f < 2304; f += 512) {
      const int oc = f / 36;
      const int f36 = f - oc * 36;
      const f32x4v v = *(const f32x4v*)(wbase + (size_t)oc * 2304 + cc * 144 + f36 * 4);
#pragma unroll
      for (int e = 0; e < 4; ++e) {
        const int flat = f36 * 4 + e;
        const int ic = flat / 9;
        const int kq = flat - ic * 9;
        As[kq * 1024 + oc * 16 + ic] = f2bf(v[e]);
      }
    }
    __syncthreads();

    // MFMA: per wave, its 3 slots; per slot, nk K-steps (one kq x 16 ic each)
#pragma unroll
    for (int slot = 0; slot < 3; ++slot) {
#pragma unroll
      for (int s = 0; s < 4; ++s) {
        if (s < nkS[slot]) {
          const int kq = kqS[slot][s];
          const bf16x8 B  = *(const bf16x8*)(xs + cellxS[slot][s] * 16 + q * 8);
          const bf16x8 Aa = *(const bf16x8*)(As + kq * 1024 + l31 * 16 + q * 8);
          const bf16x8 Ab = *(const bf16x8*)(As + kq * 1024 + (32 + l31) * 16 + q * 8);
          acc[slot][0] = __builtin_amdgcn_mfma_f32_32x32x16_bf16(Aa, B, acc[slot][0], 0, 0, 0);
          acc[slot][1] = __builtin_amdgcn_mfma_f32_32x32x16_bf16(Ab, B, acc[slot][1], 0, 0, 0);
        }
      }
    }
  }

  // ---------------- epilogue: 2 phases (mf = oc-half), h->LDS then 4x4 FIR ----------------
  const float kf4[4] = {0.25f, 0.75f, 0.75f, 0.25f};
#pragma unroll
  for (int mf = 0; mf < 2; ++mf) {
    __syncthreads();   // previous phase reads (or GEMM LDS reads) complete
    // write h (bf16): C-layout row = (e&3)+8*(e>>2)+4q = oc-local
#pragma unroll
    for (int slot = 0; slot < 3; ++slot) {
      if (validS[slot]) {
#pragma unroll
        for (int e = 0; e < 16; ++e) {
          const int ocl = (e & 3) + 8 * (e >> 2) + 4 * q;
          hl[hbaseS[slot] + ocl * 200] = f2bf(acc[slot][mf][e]);
        }
      }
    }
    __syncthreads();
    // FIR: 2048 units (ocl32 x Yl16 x g4), 4 per thread; coalesced out writes
#pragma unroll
    for (int k = 0; k < 4; ++k) {
      const int v = tid + k * 512;
      const int g = v & 3;
      const int Yl = (v >> 2) & 15;
      const int ocl = v >> 6;
      float o[8];
#pragma unroll
      for (int xx = 0; xx < 8; ++xx) o[xx] = 0.f;
#pragma unroll
      for (int du = 0; du < 4; ++du) {
        const int ttp = Yl - 1 + du;          // local fine h-row
        const int py = ttp & 1;
        const int r = py ? ((Yl + du) >> 1) : (ttp >> 1);
        const int baseE = (py * 2) * 6400 + ocl * 200 + r * 20 + 4 * g;
        const int baseO = (py * 2 + 1) * 6400 + ocl * 200 + r * 20 + 4 * g;
        const short4v e0 = *(const short4v*)(hl + baseE);
        const short4v e1 = *(const short4v*)(hl + baseE + 4);
        const short4v o0 = *(const short4v*)(hl + baseO);
        const short4v o1 = *(const short4v*)(hl + baseO + 4);
        float E[8], O[8];
#pragma unroll
        for (int i = 0; i < 4; ++i) {
          E[i] = bf2f(e0[i]); E[i + 4] = bf2f(e1[i]);
          O[i] = bf2f(o0[i]); O[i + 4] = bf2f(o1[i]);
        }
        float rx[8];
        rx[0] = 0.25f*O[0] + 0.75f*E[0] + 0.75f*O[1] + 0.25f*E[1];
        rx[1] = 0.25f*E[0] + 0.75f*O[1] + 0.75f*E[1] + 0.25f*O[2];
        rx[2] = 0.25f*O[1] + 0.75f*E[1] + 0.75f*O[2] + 0.25f*E[2];
        rx[3] = 0.25f*E[1] + 0.75f*O[2] + 0.75f*E[2] + 0.25f*O[3];
        rx[4] = 0.25f*O[2] + 0.75f*E[2] + 0.75f*O[3] + 0.25f*E[3];
        rx[5] = 0.25f*E[2] + 0.75f*O[3] + 0.75f*E[3] + 0.25f*O[4];
        rx[6] = 0.25f*O[3] + 0.75f*E[3] + 0.75f*O[4] + 0.25f*E[4];
        rx[7] = 0.25f*E[3] + 0.75f*O[4] + 0.75f*E[4] + 0.25f*O[5];
        const float ky = kf4[du];
#pragma unroll
        for (int xx = 0; xx < 8; ++xx) o[xx] += ky * rx[xx];
      }
      const int oc = octile * 64 + mf * 32 + ocl;
      const int Y = atile * 16 + Yl;
      const int X0 = btile * 32 + g * 8;
      float* op = out + (((size_t)(n * 256 + oc)) * 128 + Y) * 128 + X0;
      f32x4v v0, v1;
      v0[0] = o[0]; v0[1] = o[1]; v0[2] = o[2]; v0[3] = o[3];
      v1[0] = o[4]; v1[1] = o[5]; v1[2] = o[6]; v1[3] = o[7];
      *(f32x4v*)op = v0;
      *(f32x4v*)(op + 4) = v1;
    }
  }
}

extern "C" void kernel_launch(void* const* d_in, const int* in_sizes, int n_in,
                              void* d_out, int out_size, void* d_ws, size_t ws_size,
                              hipStream_t stream) {
  (void)in_sizes; (void)n_in; (void)out_size; (void)d_ws; (void)ws_size;
  const float* x = (const float*)d_in[0];
  const float* w = (const float*)d_in[1];
  float* out = (float*)d_out;
  // grid = 4 octiles x 4 n x 32 spatial = 512 blocks, 512 threads (8 waves)
  hipLaunchKernelGGL(fir_up_v6, dim3(512), dim3(512), 0, stream, x, w, out);
}

// Round 8
// 103.545 us; speedup vs baseline: 1.2835x; 1.2835x over previous
//
#include <hip/hip_runtime.h>

// FirUpsample R7 = R5 + b64-vectorized A-staging (R5/R6's bottleneck was the
// per-chunk A-restage issuing 144 wave-instrs of scalar ds_write_b16 + addr
// VALU; now 36 wave-instrs of conflict-free ds_write_b64).
//   Stage 1 (MFMA): h = dilated conv3x3(x, w) as 4 parity-plane GEMMs
//     (K-depth 4/2/2/1 x 256 ic => 10.3 G MAC vs 38.7 G composite form).
//   Stage 2 (VALU): separable 4-tap FIR on h (bf16 in LDS), fp32 out.
// Wave split per chunk: waves 0-3 stage A (one (oc,icg) unit per thread),
// waves 4-7 stage x. MFMA loop / plane tables / epilogue verbatim R5.

typedef short bf16x4 __attribute__((ext_vector_type(4)));
typedef short bf16x8 __attribute__((ext_vector_type(8)));
typedef short short4v __attribute__((ext_vector_type(4)));
typedef float f32x16 __attribute__((ext_vector_type(16)));
typedef float f32x4v __attribute__((ext_vector_type(4)));

static __device__ __forceinline__ short f2bf(float f) {
  union { float f; unsigned u; } v; v.f = f;
  unsigned r = (v.u + 0x7FFFu + ((v.u >> 16) & 1u)) >> 16;
  return (short)r;
}
static __device__ __forceinline__ float bf2f(short s) {
  union { unsigned u; float f; } v; v.u = ((unsigned)(unsigned short)s) << 16;
  return v.f;
}

__global__ __launch_bounds__(512)
void fir_up_v7(const float* __restrict__ x, const float* __restrict__ w,
               float* __restrict__ out) {
  // XCD swizzle: xcd = bid&7; octile-major so each XCD pair shares a w-slice.
  const int bid = blockIdx.x;
  const int wg = (bid & 7) * 64 + (bid >> 3);
  const int octile = wg >> 7;        // 0..3 (64 oc each)
  const int n = (wg >> 5) & 3;
  const int sp = wg & 31;
  const int atile = sp >> 2;         // 0..7 coarse-row tiles (8 rows each)
  const int btile = sp & 3;          // 0..3 coarse-col tiles (16 cols each)
  const int A0 = atile * 8, B0 = btile * 16;

  const int tid = threadIdx.x;
  const int wid = tid >> 6;
  const int lane = tid & 63;
  const int l31 = lane & 31, q = lane >> 5;

  __shared__ short As[9 * 64 * 16];       // [kq][oc64][ic16]  18.4 KB
  __shared__ short xs[180 * 16];          // [cell=r*18+c][ic16] 5.76 KB
  __shared__ short hl[4 * 32 * 10 * 20];  // [plane][ocl][r][c(pad 20)] 51.2 KB

  // plane geometry: p = py*2+px ; rows: even 9 odd 10 ; cols: even 17 odd 18
  const int COLSt[4]  = {17, 18, 17, 18};
  const int CELLSt[4] = {153, 162, 170, 180};
  const int NKt[4]    = {4, 2, 2, 1};
  const int KQt[4][4] = {{0,2,6,8},{1,7,7,7},{3,5,5,5},{4,4,4,4}};
  const int DYt[4][4] = {{0,0,1,1},{0,1,1,1},{0,0,0,0},{0,0,0,0}};
  const int DXt[4][4] = {{0,1,0,1},{0,0,0,0},{0,1,1,1},{0,0,0,0}};

  // per-wave frag assignment (8 waves x 3 slots), K-balanced (7,7,7,7,7,7,6,6)
  const unsigned long long PLbits =
      (0x34ULL) | (0x34ULL << 6) | (0x34ULL << 12) | (0x38ULL << 18) |
      (0x38ULL << 24) | (0x38ULL << 30) | (0x15ULL << 36) | (0x2AULL << 42);
  const unsigned FG0 = 0u | 1u<<3 | 2u<<6 | 3u<<9 | 4u<<12 | 5u<<15 | 3u<<18 | 3u<<21;
  const unsigned FG1 = 0u | 1u<<3 | 2u<<6 | 0u<<9 | 1u<<12 | 2u<<15 | 4u<<18 | 4u<<21;
  const unsigned FG2 = 0u | 1u<<3 | 2u<<6 | 3u<<9 | 4u<<12 | 5u<<15 | 5u<<18 | 5u<<21;

  int nkS[3], validS[3], hbaseS[3];
  int kqS[3][4], cellxS[3][4];
#pragma unroll
  for (int slot = 0; slot < 3; ++slot) {
    const int p = (int)((PLbits >> ((wid * 3 + slot) * 2)) & 3ULL);
    const unsigned fgw = slot == 0 ? FG0 : (slot == 1 ? FG1 : FG2);
    const int fg = (int)((fgw >> (3 * wid)) & 7u);
    const int cellraw = fg * 32 + l31;
    const int valid = cellraw < CELLSt[p];
    const int cell = valid ? cellraw : 0;
    const int cols = COLSt[p];
    const int r = cell / cols;
    const int c = cell - r * cols;
    nkS[slot] = NKt[p];
    validS[slot] = valid;
    hbaseS[slot] = p * 6400 + r * 20 + c;
#pragma unroll
    for (int s = 0; s < 4; ++s) {
      kqS[slot][s] = KQt[p][s];
      cellxS[slot][s] = (r + DYt[p][s]) * 18 + (c + DXt[p][s]);
    }
  }

  f32x16 acc[3][2];
#pragma unroll
  for (int slot = 0; slot < 3; ++slot)
#pragma unroll
    for (int mf = 0; mf < 2; ++mf)
#pragma unroll
      for (int e = 0; e < 16; ++e) acc[slot][mf][e] = 0.f;

  // A-stage constants (threads 0..255): unit = (ocA, icgA)
  const int ocA = tid >> 2;          // 0..63 (only meaningful for tid<256)
  const int icgA = tid & 3;          // 0..3 (4-ic group)
  const float* wA = w + (size_t)(octile * 64 + ocA) * 2304 + icgA * 36;

  // ---------------- K-loop: 16 chunks of 16 ic ----------------
  for (int cc = 0; cc < 16; ++cc) {
    __syncthreads();
    if (tid < 256) {
      // stage A (= w bf16): load 36 contiguous floats (9 float4), transpose in
      // regs, write 9 conflict-free ds_write_b64 at As[kq][ocA][icgA*4]
      float f36[36];
      const float* wp = wA + cc * 144;
#pragma unroll
      for (int f4 = 0; f4 < 9; ++f4)
        *(f32x4v*)&f36[f4 * 4] = *(const f32x4v*)(wp + f4 * 4);
#pragma unroll
      for (int kq = 0; kq < 9; ++kq) {
        bf16x4 pk;
#pragma unroll
        for (int v = 0; v < 4; ++v) pk[v] = f2bf(f36[v * 9 + kq]);
        *(bf16x4*)(As + kq * 1024 + ocA * 16 + icgA * 4) = pk;
      }
    } else {
      // stage x tile: rows [A0-1, A0+8], cols [B0-1, B0+16] -> 10x18 cells x 16 ic
      for (int u = tid - 256; u < 360; u += 256) {
        const int cell = u >> 1, half = u & 1;
        const int hh = cell / 18, ww = cell - hh * 18;
        const int gh = A0 - 1 + hh, gw = B0 - 1 + ww;
        const bool ok = (gh >= 0) & (gh < 64) & (gw >= 0) & (gw < 64);
        const float* xp = x + (((size_t)(n * 256 + cc * 16 + half * 8)) * 64 + gh) * 64 + gw;
        bf16x8 vv;
#pragma unroll
        for (int e = 0; e < 8; ++e) {
          const float f = ok ? xp[(size_t)e * 4096] : 0.f;
          vv[e] = f2bf(f);
        }
        *(bf16x8*)(xs + cell * 16 + half * 8) = vv;
      }
    }
    __syncthreads();

    // MFMA: per wave, its 3 slots; per slot, nk K-steps (one kq x 16 ic each)
#pragma unroll
    for (int slot = 0; slot < 3; ++slot) {
#pragma unroll
      for (int s = 0; s < 4; ++s) {
        if (s < nkS[slot]) {
          const int kq = kqS[slot][s];
          const bf16x8 B  = *(const bf16x8*)(xs + cellxS[slot][s] * 16 + q * 8);
          const bf16x8 Aa = *(const bf16x8*)(As + kq * 1024 + l31 * 16 + q * 8);
          const bf16x8 Ab = *(const bf16x8*)(As + kq * 1024 + (32 + l31) * 16 + q * 8);
          acc[slot][0] = __builtin_amdgcn_mfma_f32_32x32x16_bf16(Aa, B, acc[slot][0], 0, 0, 0);
          acc[slot][1] = __builtin_amdgcn_mfma_f32_32x32x16_bf16(Ab, B, acc[slot][1], 0, 0, 0);
        }
      }
    }
  }

  // ---------------- epilogue: 2 phases (mf = oc-half), h->LDS then 4x4 FIR ----------------
  const float kf4[4] = {0.25f, 0.75f, 0.75f, 0.25f};
#pragma unroll
  for (int mf = 0; mf < 2; ++mf) {
    __syncthreads();   // previous phase reads (or GEMM LDS reads) complete
    // write h (bf16): C-layout row = (e&3)+8*(e>>2)+4q = oc-local
#pragma unroll
    for (int slot = 0; slot < 3; ++slot) {
      if (validS[slot]) {
#pragma unroll
        for (int e = 0; e < 16; ++e) {
          const int ocl = (e & 3) + 8 * (e >> 2) + 4 * q;
          hl[hbaseS[slot] + ocl * 200] = f2bf(acc[slot][mf][e]);
        }
      }
    }
    __syncthreads();
    // FIR: 2048 units (ocl32 x Yl16 x g4), 4 per thread; coalesced out writes
#pragma unroll
    for (int k = 0; k < 4; ++k) {
      const int v = tid + k * 512;
      const int g = v & 3;
      const int Yl = (v >> 2) & 15;
      const int ocl = v >> 6;
      float o[8];
#pragma unroll
      for (int xx = 0; xx < 8; ++xx) o[xx] = 0.f;
#pragma unroll
      for (int du = 0; du < 4; ++du) {
        const int ttp = Yl - 1 + du;          // local fine h-row
        const int py = ttp & 1;
        const int r = py ? ((Yl + du) >> 1) : (ttp >> 1);
        const int baseE = (py * 2) * 6400 + ocl * 200 + r * 20 + 4 * g;
        const int baseO = (py * 2 + 1) * 6400 + ocl * 200 + r * 20 + 4 * g;
        const short4v e0 = *(const short4v*)(hl + baseE);
        const short4v e1 = *(const short4v*)(hl + baseE + 4);
        const short4v o0 = *(const short4v*)(hl + baseO);
        const short4v o1 = *(const short4v*)(hl + baseO + 4);
        float E[8], O[8];
#pragma unroll
        for (int i = 0; i < 4; ++i) {
          E[i] = bf2f(e0[i]); E[i + 4] = bf2f(e1[i]);
          O[i] = bf2f(o0[i]); O[i + 4] = bf2f(o1[i]);
        }
        float rx[8];
        rx[0] = 0.25f*O[0] + 0.75f*E[0] + 0.75f*O[1] + 0.25f*E[1];
        rx[1] = 0.25f*E[0] + 0.75f*O[1] + 0.75f*E[1] + 0.25f*O[2];
        rx[2] = 0.25f*O[1] + 0.75f*E[1] + 0.75f*O[2] + 0.25f*E[2];
        rx[3] = 0.25f*E[1] + 0.75f*O[2] + 0.75f*E[2] + 0.25f*O[3];
        rx[4] = 0.25f*O[2] + 0.75f*E[2] + 0.75f*O[3] + 0.25f*E[3];
        rx[5] = 0.25f*E[2] + 0.75f*O[3] + 0.75f*E[3] + 0.25f*O[4];
        rx[6] = 0.25f*O[3] + 0.75f*E[3] + 0.75f*O[4] + 0.25f*E[4];
        rx[7] = 0.25f*E[3] + 0.75f*O[4] + 0.75f*E[4] + 0.25f*O[5];
        const float ky = kf4[du];
#pragma unroll
        for (int xx = 0; xx < 8; ++xx) o[xx] += ky * rx[xx];
      }
      const int oc = octile * 64 + mf * 32 + ocl;
      const int Y = atile * 16 + Yl;
      const int X0 = btile * 32 + g * 8;
      float* op = out + (((size_t)(n * 256 + oc)) * 128 + Y) * 128 + X0;
      f32x4v v0, v1;
      v0[0] = o[0]; v0[1] = o[1]; v0[2] = o[2]; v0[3] = o[3];
      v1[0] = o[4]; v1[1] = o[5]; v1[2] = o[6]; v1[3] = o[7];
      *(f32x4v*)op = v0;
      *(f32x4v*)(op + 4) = v1;
    }
  }
}

extern "C" void kernel_launch(void* const* d_in, const int* in_sizes, int n_in,
                              void* d_out, int out_size, void* d_ws, size_t ws_size,
                              hipStream_t stream) {
  (void)in_sizes; (void)n_in; (void)out_size; (void)d_ws; (void)ws_size;
  const float* x = (const float*)d_in[0];
  const float* w = (const float*)d_in[1];
  float* out = (float*)d_out;
  // grid = 4 octiles x 4 n x 32 spatial = 512 blocks, 512 threads (8 waves)
  hipLaunchKernelGGL(fir_up_v7, dim3(512), dim3(512), 0, stream, x, w, out);
}